// Round 1
// baseline (386.511 us; speedup 1.0000x reference)
//
#include <hip/hip_runtime.h>
#include <hip/hip_bf16.h>

#define D_MODEL 1024
#define NHEAD   16
#define HDIM    64
#define SEQQ    2048
#define NBATCH  2
#define MROWS   (NBATCH * SEQQ)   // 4096

typedef unsigned short u16;
typedef __attribute__((ext_vector_type(8))) short short8;   // 8 bf16 (4 VGPRs)
typedef __attribute__((ext_vector_type(4))) float floatx4;  // 4 fp32 acc

__device__ __forceinline__ u16 f2b(float f) {
    union { __hip_bfloat16 h; u16 u; } cv;
    cv.h = __float2bfloat16(f);
    return cv.u;
}
__device__ __forceinline__ float b2f(u16 u) {
    return __uint_as_float(((unsigned int)u) << 16);
}
__device__ __forceinline__ short8 load8(const u16* p) {
    return *reinterpret_cast<const short8*>(p);
}
__device__ __forceinline__ void async_cp16(const void* g, void* l) {
    __builtin_amdgcn_global_load_lds(
        (const __attribute__((address_space(1))) void*)g,
        (__attribute__((address_space(3))) void*)l, 16, 0, 0);
}

// ---------------- fp32 -> bf16 convert ----------------
__global__ void cvt_kernel(const float* __restrict__ in, u16* __restrict__ out, int n4) {
    int i = blockIdx.x * blockDim.x + threadIdx.x;
    if (i >= n4) return;
    float4 v = reinterpret_cast<const float4*>(in)[i];
    ushort4 o;
    o.x = f2b(v.x); o.y = f2b(v.y); o.z = f2b(v.z); o.w = f2b(v.w);
    reinterpret_cast<ushort4*>(out)[i] = o;
}

// ---------------- GEMM: C = A(MxK) * Bt(NxK)^T, m97-style 128x128 tile ----------------
template <int WRITE_F32>
__global__ __launch_bounds__(256) void gemm_bt(
    const u16* __restrict__ A,
    const u16* __restrict__ B0, const u16* __restrict__ B1, const u16* __restrict__ B2,
    void* __restrict__ C0, void* __restrict__ C1, void* __restrict__ C2,
    int M, int N, int K)
{
    const u16* Bt = (blockIdx.z == 0) ? B0 : (blockIdx.z == 1 ? B1 : B2);
    void*      Cp = (blockIdx.z == 0) ? C0 : (blockIdx.z == 1 ? C1 : C2);

    __shared__ __attribute__((aligned(16))) u16 As[128 * 32];
    __shared__ __attribute__((aligned(16))) u16 Bs[128 * 32];

    const int tid  = threadIdx.x;
    const int w    = tid >> 6;
    const int lane = tid & 63;
    const int l15  = lane & 15;
    const int quad = lane >> 4;
    const int wm   = w >> 1, wn = w & 1;
    const int tm   = blockIdx.x * 128, tn = blockIdx.y * 128;

    floatx4 acc[4][4];
#pragma unroll
    for (int i = 0; i < 4; i++)
#pragma unroll
        for (int j = 0; j < 4; j++) {
            floatx4 z = {0.f, 0.f, 0.f, 0.f};
            acc[i][j] = z;
        }

    const int srow = lane >> 2;        // 0..15
    const int scol = (lane & 3) * 8;   // 0,8,16,24

    for (int k0 = 0; k0 < K; k0 += 32) {
#pragma unroll
        for (int ch = w; ch < 8; ch += 4) {   // each wave stages 2x1KB chunks of A and B
            async_cp16(A  + (size_t)(tm + ch * 16 + srow) * K + k0 + scol, &As[ch * 512]);
            async_cp16(Bt + (size_t)(tn + ch * 16 + srow) * K + k0 + scol, &Bs[ch * 512]);
        }
        __syncthreads();   // vmcnt(0) drain + barrier

        short8 af[4], bfr[4];
#pragma unroll
        for (int mi = 0; mi < 4; mi++)
            af[mi] = load8(&As[(wm * 64 + mi * 16 + l15) * 32 + quad * 8]);
#pragma unroll
        for (int ni = 0; ni < 4; ni++)
            bfr[ni] = load8(&Bs[(wn * 64 + ni * 16 + l15) * 32 + quad * 8]);
#pragma unroll
        for (int mi = 0; mi < 4; mi++)
#pragma unroll
            for (int ni = 0; ni < 4; ni++)
                acc[mi][ni] = __builtin_amdgcn_mfma_f32_16x16x32_bf16(af[mi], bfr[ni], acc[mi][ni], 0, 0, 0);
        __syncthreads();
    }

#pragma unroll
    for (int mi = 0; mi < 4; mi++)
#pragma unroll
        for (int ni = 0; ni < 4; ni++)
#pragma unroll
            for (int rg = 0; rg < 4; rg++) {
                int row = tm + wm * 64 + mi * 16 + quad * 4 + rg;  // C/D: row=quad*4+reg
                int col = tn + wn * 64 + ni * 16 + l15;            //      col=lane&15
                float v = acc[mi][ni][rg];
                if (WRITE_F32) reinterpret_cast<float*>(Cp)[(size_t)row * N + col] = v;
                else           reinterpret_cast<u16*>(Cp)[(size_t)row * N + col]   = f2b(v);
            }
}

// ---------------- RoPE + [b,s,h,d] -> [b,h,s,d] transpose for Q and K ----------------
__global__ void rope_qk(const u16* __restrict__ Qraw, const u16* __restrict__ Kraw,
                        const int* __restrict__ pos, u16* __restrict__ Qt, u16* __restrict__ Kt)
{
    const int gid = blockIdx.x * 256 + threadIdx.x;  // 2^21 threads
    const int j = gid & 31;
    const int s = (gid >> 5) & (SEQQ - 1);
    const int h = (gid >> 16) & (NHEAD - 1);
    const int b = gid >> 20;

    const float p   = (float)pos[s];
    const float inv = expf(-(float)j * (9.210340371976184f / 32.0f));  // 10000^(-j/32)
    float sn, cs;
    sincosf(p * inv, &sn, &cs);

    const size_t ioff = ((size_t)(b * SEQQ + s)) * D_MODEL + h * HDIM + 2 * j;
    const ushort2 qp = *reinterpret_cast<const ushort2*>(&Qraw[ioff]);
    const ushort2 kp = *reinterpret_cast<const ushort2*>(&Kraw[ioff]);
    const float qe = b2f(qp.x), qo = b2f(qp.y);
    const float ke = b2f(kp.x), ko = b2f(kp.y);

    const size_t ooff = (((size_t)(b * NHEAD + h)) * SEQQ + s) * HDIM + 2 * j;
    ushort2 qr; qr.x = f2b(qe * cs - qo * sn); qr.y = f2b(qe * sn + qo * cs);
    ushort2 kr; kr.x = f2b(ke * cs - ko * sn); kr.y = f2b(ke * sn + ko * cs);
    *reinterpret_cast<ushort2*>(&Qt[ooff]) = qr;
    *reinterpret_cast<ushort2*>(&Kt[ooff]) = kr;
}

// ---------------- V: [b,s,h*d] -> [b,h,d,s] transpose ----------------
__global__ __launch_bounds__(256) void vtrans(const u16* __restrict__ Vraw, u16* __restrict__ Vt)
{
    __shared__ u16 tile[64][65];
    const int s0 = blockIdx.x * 64, h = blockIdx.y, b = blockIdx.z;
    const int t = threadIdx.x;
#pragma unroll
    for (int i = 0; i < 16; i++) {
        int idx = t + i * 256;
        int sl = idx >> 6, dl = idx & 63;
        tile[sl][dl] = Vraw[((size_t)(b * SEQQ + s0 + sl)) * D_MODEL + h * HDIM + dl];
    }
    __syncthreads();
#pragma unroll
    for (int i = 0; i < 16; i++) {
        int idx = t + i * 256;
        int dl = idx >> 6, sl = idx & 63;
        Vt[(((size_t)(b * NHEAD + h)) * HDIM + dl) * SEQQ + s0 + sl] = tile[sl][dl];
    }
}

// ---------------- causal flash attention: one block = 64 q rows, 4 waves x 16 rows ----------------
__global__ __launch_bounds__(256) void attn_kernel(
    const u16* __restrict__ Qt, const u16* __restrict__ Kt, const u16* __restrict__ Vt,
    u16* __restrict__ Out)
{
    const int qblk = blockIdx.x, h = blockIdx.y, b = blockIdx.z;
    const int tid = threadIdx.x, w = tid >> 6, lane = tid & 63;
    const int l15 = lane & 15, quad = lane >> 4;
    const size_t bh = (size_t)(b * NHEAD + h);
    const u16* Qh = Qt + bh * SEQQ * HDIM;
    const u16* Kh = Kt + bh * SEQQ * HDIM;
    const u16* Vh = Vt + bh * HDIM * SEQQ;   // [d][s]
    const int q0w = qblk * 64 + w * 16;

    short8 qf[2];
#pragma unroll
    for (int kk = 0; kk < 2; kk++)
        qf[kk] = load8(&Qh[(size_t)(q0w + l15) * HDIM + kk * 32 + quad * 8]);

    floatx4 O[4];
    float m_i[4], l_i[4];
#pragma unroll
    for (int c = 0; c < 4; c++) { floatx4 z = {0.f, 0.f, 0.f, 0.f}; O[c] = z; }
#pragma unroll
    for (int r = 0; r < 4; r++) { m_i[r] = -1e30f; l_i[r] = 0.f; }

    __shared__ __attribute__((aligned(16))) u16 Plds[4][16 * 32];  // per-wave P tile

    const int ntiles = qblk * 2 + 2;  // keys up to and including the diagonal block
    for (int t = 0; t < ntiles; ++t) {
        const int k0 = t * 32;
        floatx4 S[2];
        { floatx4 z = {0.f, 0.f, 0.f, 0.f}; S[0] = z; S[1] = z; }
#pragma unroll
        for (int c = 0; c < 2; c++)
#pragma unroll
            for (int kk = 0; kk < 2; kk++) {
                short8 kf = load8(&Kh[(size_t)(k0 + c * 16 + l15) * HDIM + kk * 32 + quad * 8]);
                S[c] = __builtin_amdgcn_mfma_f32_16x16x32_bf16(qf[kk], kf, S[c], 0, 0, 0);
            }
        // scale + causal mask; rows: q = q0w + quad*4 + r, cols: key = k0 + c*16 + l15
        float mt[4];
#pragma unroll
        for (int r = 0; r < 4; r++) {
            const int q = q0w + quad * 4 + r;
#pragma unroll
            for (int c = 0; c < 2; c++) {
                float s = S[c][r] * 0.125f;
                if (k0 + c * 16 + l15 > q) s = -1e30f;
                S[c][r] = s;
            }
            mt[r] = fmaxf(S[0][r], S[1][r]);
        }
#pragma unroll
        for (int off = 1; off < 16; off <<= 1)
#pragma unroll
            for (int r = 0; r < 4; r++)
                mt[r] = fmaxf(mt[r], __shfl_xor(mt[r], off, 64));

        float alpha[4], rs[4];
#pragma unroll
        for (int r = 0; r < 4; r++) {
            float mn = fmaxf(m_i[r], mt[r]);
            alpha[r] = __expf(m_i[r] - mn);
            m_i[r] = mn;
            float p0 = __expf(S[0][r] - mn);
            float p1 = __expf(S[1][r] - mn);
            S[0][r] = p0; S[1][r] = p1;
            rs[r] = p0 + p1;
        }
#pragma unroll
        for (int off = 1; off < 16; off <<= 1)
#pragma unroll
            for (int r = 0; r < 4; r++)
                rs[r] += __shfl_xor(rs[r], off, 64);
#pragma unroll
        for (int r = 0; r < 4; r++) l_i[r] = l_i[r] * alpha[r] + rs[r];
#pragma unroll
        for (int c2 = 0; c2 < 4; c2++)
#pragma unroll
            for (int r = 0; r < 4; r++)
                O[c2][r] *= alpha[r];

        // P: C-layout -> LDS -> A-layout
#pragma unroll
        for (int c = 0; c < 2; c++)
#pragma unroll
            for (int r = 0; r < 4; r++)
                Plds[w][(quad * 4 + r) * 32 + c * 16 + l15] = f2b(S[c][r]);
        __syncthreads();
        short8 pf = load8(&Plds[w][l15 * 32 + quad * 8]);
#pragma unroll
        for (int c2 = 0; c2 < 4; c2++) {
            short8 vf = load8(&Vh[(size_t)(c2 * 16 + l15) * SEQQ + k0 + quad * 8]);
            O[c2] = __builtin_amdgcn_mfma_f32_16x16x32_bf16(pf, vf, O[c2], 0, 0, 0);
        }
        __syncthreads();
    }

    // epilogue: out[b, q, h*64+d] = O / l  (bf16, feeds o_proj GEMM)
#pragma unroll
    for (int c2 = 0; c2 < 4; c2++)
#pragma unroll
        for (int r = 0; r < 4; r++) {
            const int q   = q0w + quad * 4 + r;
            const int col = h * HDIM + c2 * 16 + l15;
            Out[(size_t)(b * SEQQ + q) * D_MODEL + col] = f2b(O[c2][r] / l_i[r]);
        }
}

// ---------------- launch ----------------
extern "C" void kernel_launch(void* const* d_in, const int* in_sizes, int n_in,
                              void* d_out, int out_size, void* d_ws, size_t ws_size,
                              hipStream_t stream)
{
    const float* X  = (const float*)d_in[0];
    const float* Wq = (const float*)d_in[1];
    const float* Wk = (const float*)d_in[2];
    const float* Wv = (const float*)d_in[3];
    const float* Wo = (const float*)d_in[4];
    const int* tpos = (const int*)d_in[5];
    float* out = (float*)d_out;
    char* ws = (char*)d_ws;

    const size_t MB = (size_t)1 << 20;
    u16* Xb   = (u16*)(ws + 0);        // 8 MB; reused as Vt after proj GEMMs
    u16* WqB  = (u16*)(ws + 8 * MB);
    u16* WkB  = (u16*)(ws + 10 * MB);
    u16* WvB  = (u16*)(ws + 12 * MB);
    u16* WoB  = (u16*)(ws + 14 * MB);
    u16* Qraw = (u16*)(ws + 16 * MB);  // 8 MB; reused as AttnOut after rope
    u16* Kraw = (u16*)(ws + 24 * MB);
    u16* Vraw = (u16*)(ws + 32 * MB);
    u16* Qt   = (u16*)(ws + 40 * MB);
    u16* Kt   = (u16*)(ws + 48 * MB);
    u16* Vt   = Xb;
    u16* AOut = Qraw;

    cvt_kernel<<<4096, 256, 0, stream>>>(X,  Xb,  MROWS * D_MODEL / 4);
    cvt_kernel<<<1024, 256, 0, stream>>>(Wq, WqB, D_MODEL * D_MODEL / 4);
    cvt_kernel<<<1024, 256, 0, stream>>>(Wk, WkB, D_MODEL * D_MODEL / 4);
    cvt_kernel<<<1024, 256, 0, stream>>>(Wv, WvB, D_MODEL * D_MODEL / 4);
    cvt_kernel<<<1024, 256, 0, stream>>>(Wo, WoB, D_MODEL * D_MODEL / 4);

    gemm_bt<0><<<dim3(32, 8, 3), 256, 0, stream>>>(Xb, WqB, WkB, WvB,
                                                   Qraw, Kraw, Vraw,
                                                   MROWS, D_MODEL, D_MODEL);
    rope_qk<<<8192, 256, 0, stream>>>(Qraw, Kraw, tpos, Qt, Kt);
    vtrans<<<dim3(32, 16, 2), 256, 0, stream>>>(Vraw, Vt);
    attn_kernel<<<dim3(32, 16, 2), 256, 0, stream>>>(Qt, Kt, Vt, AOut);
    gemm_bt<1><<<dim3(32, 8, 1), 256, 0, stream>>>(AOut, WoB, WoB, WoB,
                                                   out, out, out,
                                                   MROWS, D_MODEL, D_MODEL);
}

// Round 2
// 377.418 us; speedup vs baseline: 1.0241x; 1.0241x over previous
//
#include <hip/hip_runtime.h>
#include <hip/hip_bf16.h>

#define D_MODEL 1024
#define NHEAD   16
#define HDIM    64
#define SEQQ    2048
#define NBATCH  2
#define MROWS   (NBATCH * SEQQ)   // 4096

typedef unsigned short u16;
typedef __attribute__((ext_vector_type(8))) short short8;   // 8 bf16 (4 VGPRs)
typedef __attribute__((ext_vector_type(4))) float floatx4;  // 4 fp32 acc

__device__ __forceinline__ u16 f2b(float f) {
    union { __hip_bfloat16 h; u16 u; } cv;
    cv.h = __float2bfloat16(f);
    return cv.u;
}
__device__ __forceinline__ float b2f(u16 u) {
    return __uint_as_float(((unsigned int)u) << 16);
}
__device__ __forceinline__ short8 load8(const u16* p) {
    return *reinterpret_cast<const short8*>(p);
}
__device__ __forceinline__ void async_cp16(const void* g, void* l) {
    __builtin_amdgcn_global_load_lds(
        (const __attribute__((address_space(1))) void*)g,
        (__attribute__((address_space(3))) void*)l, 16, 0, 0);
}

// ---------------- fp32 -> bf16 convert (X) ----------------
__global__ void cvt_kernel(const float* __restrict__ in, u16* __restrict__ out, int n4) {
    int i = blockIdx.x * blockDim.x + threadIdx.x;
    if (i >= n4) return;
    float4 v = reinterpret_cast<const float4*>(in)[i];
    ushort4 o;
    o.x = f2b(v.x); o.y = f2b(v.y); o.z = f2b(v.z); o.w = f2b(v.w);
    reinterpret_cast<ushort4*>(out)[i] = o;
}

// ---------------- fp32 -> bf16 convert, 4 weight matrices in one dispatch ----------------
__global__ void cvt4_kernel(const float* __restrict__ i0, const float* __restrict__ i1,
                            const float* __restrict__ i2, const float* __restrict__ i3,
                            u16* __restrict__ o0, u16* __restrict__ o1,
                            u16* __restrict__ o2, u16* __restrict__ o3, int n4) {
    const int z = blockIdx.y;
    const float* in = (z == 0) ? i0 : (z == 1) ? i1 : (z == 2) ? i2 : i3;
    u16* out = (z == 0) ? o0 : (z == 1) ? o1 : (z == 2) ? o2 : o3;
    int i = blockIdx.x * blockDim.x + threadIdx.x;
    if (i >= n4) return;
    float4 v = reinterpret_cast<const float4*>(in)[i];
    ushort4 o;
    o.x = f2b(v.x); o.y = f2b(v.y); o.z = f2b(v.z); o.w = f2b(v.w);
    reinterpret_cast<ushort4*>(out)[i] = o;
}

// ---------------- GEMM: C = A(MxK) * Bt(NxK)^T, m97-style 128x128 tile ----------------
template <int WRITE_F32>
__global__ __launch_bounds__(256) void gemm_bt(
    const u16* __restrict__ A,
    const u16* __restrict__ B0, const u16* __restrict__ B1, const u16* __restrict__ B2,
    void* __restrict__ C0, void* __restrict__ C1, void* __restrict__ C2,
    int M, int N, int K)
{
    const u16* Bt = (blockIdx.z == 0) ? B0 : (blockIdx.z == 1 ? B1 : B2);
    void*      Cp = (blockIdx.z == 0) ? C0 : (blockIdx.z == 1 ? C1 : C2);

    __shared__ __attribute__((aligned(16))) u16 As[128 * 32];
    __shared__ __attribute__((aligned(16))) u16 Bs[128 * 32];

    const int tid  = threadIdx.x;
    const int w    = tid >> 6;
    const int lane = tid & 63;
    const int l15  = lane & 15;
    const int quad = lane >> 4;
    const int wm   = w >> 1, wn = w & 1;
    const int tm   = blockIdx.x * 128, tn = blockIdx.y * 128;

    floatx4 acc[4][4];
#pragma unroll
    for (int i = 0; i < 4; i++)
#pragma unroll
        for (int j = 0; j < 4; j++) {
            floatx4 z = {0.f, 0.f, 0.f, 0.f};
            acc[i][j] = z;
        }

    const int srow = lane >> 2;        // 0..15
    const int scol = (lane & 3) * 8;   // 0,8,16,24

    for (int k0 = 0; k0 < K; k0 += 32) {
#pragma unroll
        for (int ch = w; ch < 8; ch += 4) {
            async_cp16(A  + (size_t)(tm + ch * 16 + srow) * K + k0 + scol, &As[ch * 512]);
            async_cp16(Bt + (size_t)(tn + ch * 16 + srow) * K + k0 + scol, &Bs[ch * 512]);
        }
        __syncthreads();

        short8 af[4], bfr[4];
#pragma unroll
        for (int mi = 0; mi < 4; mi++)
            af[mi] = load8(&As[(wm * 64 + mi * 16 + l15) * 32 + quad * 8]);
#pragma unroll
        for (int ni = 0; ni < 4; ni++)
            bfr[ni] = load8(&Bs[(wn * 64 + ni * 16 + l15) * 32 + quad * 8]);
#pragma unroll
        for (int mi = 0; mi < 4; mi++)
#pragma unroll
            for (int ni = 0; ni < 4; ni++)
                acc[mi][ni] = __builtin_amdgcn_mfma_f32_16x16x32_bf16(af[mi], bfr[ni], acc[mi][ni], 0, 0, 0);
        __syncthreads();
    }

#pragma unroll
    for (int mi = 0; mi < 4; mi++)
#pragma unroll
        for (int ni = 0; ni < 4; ni++)
#pragma unroll
            for (int rg = 0; rg < 4; rg++) {
                int row = tm + wm * 64 + mi * 16 + quad * 4 + rg;
                int col = tn + wn * 64 + ni * 16 + l15;
                float v = acc[mi][ni][rg];
                if (WRITE_F32) reinterpret_cast<float*>(Cp)[(size_t)row * N + col] = v;
                else           reinterpret_cast<u16*>(Cp)[(size_t)row * N + col]   = f2b(v);
            }
}

// ---------------- RoPE + [b,s,h,d] -> [b,h,s,d] transpose; Q pre-scaled by 1/sqrt(d) ----------------
__global__ void rope_qk(const u16* __restrict__ Qraw, const u16* __restrict__ Kraw,
                        const int* __restrict__ pos, u16* __restrict__ Qt, u16* __restrict__ Kt)
{
    const int gid = blockIdx.x * 256 + threadIdx.x;
    const int j = gid & 31;
    const int s = (gid >> 5) & (SEQQ - 1);
    const int h = (gid >> 16) & (NHEAD - 1);
    const int b = gid >> 20;

    const float p   = (float)pos[s];
    const float inv = expf(-(float)j * (9.210340371976184f / 32.0f));
    float sn, cs;
    sincosf(p * inv, &sn, &cs);

    const size_t ioff = ((size_t)(b * SEQQ + s)) * D_MODEL + h * HDIM + 2 * j;
    const ushort2 qp = *reinterpret_cast<const ushort2*>(&Qraw[ioff]);
    const ushort2 kp = *reinterpret_cast<const ushort2*>(&Kraw[ioff]);
    const float qe = b2f(qp.x), qo = b2f(qp.y);
    const float ke = b2f(kp.x), ko = b2f(kp.y);

    const size_t ooff = (((size_t)(b * NHEAD + h)) * SEQQ + s) * HDIM + 2 * j;
    ushort2 qr;  // fold 1/sqrt(HDIM)=0.125 into Q (exponent-exact in bf16)
    qr.x = f2b((qe * cs - qo * sn) * 0.125f);
    qr.y = f2b((qe * sn + qo * cs) * 0.125f);
    ushort2 kr;
    kr.x = f2b(ke * cs - ko * sn);
    kr.y = f2b(ke * sn + ko * cs);
    *reinterpret_cast<ushort2*>(&Qt[ooff]) = qr;
    *reinterpret_cast<ushort2*>(&Kt[ooff]) = kr;
}

// ---------------- V: [b,s,h*d] -> [b,h,d,s] transpose ----------------
__global__ __launch_bounds__(256) void vtrans(const u16* __restrict__ Vraw, u16* __restrict__ Vt)
{
    __shared__ u16 tile[64][65];
    const int s0 = blockIdx.x * 64, h = blockIdx.y, b = blockIdx.z;
    const int t = threadIdx.x;
#pragma unroll
    for (int i = 0; i < 16; i++) {
        int idx = t + i * 256;
        int sl = idx >> 6, dl = idx & 63;
        tile[sl][dl] = Vraw[((size_t)(b * SEQQ + s0 + sl)) * D_MODEL + h * HDIM + dl];
    }
    __syncthreads();
#pragma unroll
    for (int i = 0; i < 16; i++) {
        int idx = t + i * 256;
        int dl = idx >> 6, sl = idx & 63;
        Vt[(((size_t)(b * NHEAD + h)) * HDIM + dl) * SEQQ + s0 + sl] = tile[sl][dl];
    }
}

// ---------------- causal flash attention v2 ----------------
// block = 64 q rows (4 independent waves x 16 rows), 64-key tiles, NO barriers.
// Plds stride 72 u16 = 144B: rows 16B-aligned, store banks = quad*8 + l15/2 -> conflict-free.
#define PSTRIDE 72
__global__ __launch_bounds__(256) void attn_kernel(
    const u16* __restrict__ Qt, const u16* __restrict__ Kt, const u16* __restrict__ Vt,
    u16* __restrict__ Out)
{
    const int qblk = (gridDim.x - 1) - blockIdx.x;   // longest blocks launch first
    const int h = blockIdx.y, b = blockIdx.z;
    const int tid = threadIdx.x, w = tid >> 6, lane = tid & 63;
    const int l15 = lane & 15, quad = lane >> 4;
    const size_t bh = (size_t)(b * NHEAD + h);
    const u16* Qh = Qt + bh * SEQQ * HDIM;
    const u16* Kh = Kt + bh * SEQQ * HDIM;
    const u16* Vh = Vt + bh * HDIM * SEQQ;   // [d][s]
    const int q0w = qblk * 64 + w * 16;

    short8 qf[2];
#pragma unroll
    for (int kk = 0; kk < 2; kk++)
        qf[kk] = load8(&Qh[(size_t)(q0w + l15) * HDIM + kk * 32 + quad * 8]);

    floatx4 O[4];
    float m_i[4], l_i[4];
#pragma unroll
    for (int c = 0; c < 4; c++) { floatx4 z = {0.f, 0.f, 0.f, 0.f}; O[c] = z; }
#pragma unroll
    for (int r = 0; r < 4; r++) { m_i[r] = -1e30f; l_i[r] = 0.f; }

    __shared__ __attribute__((aligned(16))) u16 Plds[4][16 * PSTRIDE];  // per-wave

    for (int t = 0; t <= qblk; ++t) {
        const int k0 = t * 64;
        const bool masked = (t == qblk);

        // ---- S = Q K^T for 64 keys (4 sub-tiles of 16) ----
        floatx4 S[4];
#pragma unroll
        for (int c = 0; c < 4; c++) {
            floatx4 z = {0.f, 0.f, 0.f, 0.f};
            S[c] = z;
            const u16* kp = &Kh[(size_t)(k0 + c * 16 + l15) * HDIM + quad * 8];
            S[c] = __builtin_amdgcn_mfma_f32_16x16x32_bf16(qf[0], load8(kp), S[c], 0, 0, 0);
            S[c] = __builtin_amdgcn_mfma_f32_16x16x32_bf16(qf[1], load8(kp + 32), S[c], 0, 0, 0);
        }
        if (masked) {
#pragma unroll
            for (int r = 0; r < 4; r++) {
                const int q = q0w + quad * 4 + r;
#pragma unroll
                for (int c = 0; c < 4; c++)
                    if (k0 + c * 16 + l15 > q) S[c][r] = -1e30f;
            }
        }

        // ---- row max over 64 keys ----
        float mt[4];
#pragma unroll
        for (int r = 0; r < 4; r++)
            mt[r] = fmaxf(fmaxf(S[0][r], S[1][r]), fmaxf(S[2][r], S[3][r]));
#pragma unroll
        for (int off = 1; off < 16; off <<= 1)
#pragma unroll
            for (int r = 0; r < 4; r++)
                mt[r] = fmaxf(mt[r], __shfl_xor(mt[r], off, 16));

        float alpha[4];
#pragma unroll
        for (int r = 0; r < 4; r++) {
            const float mn = fmaxf(m_i[r], mt[r]);
            alpha[r] = __expf(m_i[r] - mn);
            m_i[r] = mn;
        }
        // ---- exp + row sum ----
        float rs[4];
#pragma unroll
        for (int c = 0; c < 4; c++)
#pragma unroll
            for (int r = 0; r < 4; r++)
                S[c][r] = __expf(S[c][r] - m_i[r]);
#pragma unroll
        for (int r = 0; r < 4; r++)
            rs[r] = (S[0][r] + S[1][r]) + (S[2][r] + S[3][r]);
#pragma unroll
        for (int off = 1; off < 16; off <<= 1)
#pragma unroll
            for (int r = 0; r < 4; r++)
                rs[r] += __shfl_xor(rs[r], off, 16);
#pragma unroll
        for (int r = 0; r < 4; r++) l_i[r] = l_i[r] * alpha[r] + rs[r];
#pragma unroll
        for (int c2 = 0; c2 < 4; c2++)
#pragma unroll
            for (int r = 0; r < 4; r++)
                O[c2][r] *= alpha[r];

        // ---- P: C-layout -> LDS -> A-layout (wave-local, no barrier) ----
#pragma unroll
        for (int c = 0; c < 4; c++)
#pragma unroll
            for (int r = 0; r < 4; r++)
                Plds[w][(quad * 4 + r) * PSTRIDE + c * 16 + l15] = f2b(S[c][r]);
        const short8 pf0 = load8(&Plds[w][l15 * PSTRIDE + quad * 8]);
        const short8 pf1 = load8(&Plds[w][l15 * PSTRIDE + 32 + quad * 8]);

        // ---- O += P V ----
#pragma unroll
        for (int c2 = 0; c2 < 4; c2++) {
            const u16* vp = &Vh[(size_t)(c2 * 16 + l15) * SEQQ + k0 + quad * 8];
            O[c2] = __builtin_amdgcn_mfma_f32_16x16x32_bf16(pf0, load8(vp), O[c2], 0, 0, 0);
            O[c2] = __builtin_amdgcn_mfma_f32_16x16x32_bf16(pf1, load8(vp + 32), O[c2], 0, 0, 0);
        }
    }

    // epilogue: out[b, q, h*64+d] = O / l  (bf16, feeds o_proj GEMM)
#pragma unroll
    for (int c2 = 0; c2 < 4; c2++)
#pragma unroll
        for (int r = 0; r < 4; r++) {
            const int q   = q0w + quad * 4 + r;
            const int col = h * HDIM + c2 * 16 + l15;
            Out[(size_t)(b * SEQQ + q) * D_MODEL + col] = f2b(O[c2][r] / l_i[r]);
        }
}

// ---------------- launch ----------------
extern "C" void kernel_launch(void* const* d_in, const int* in_sizes, int n_in,
                              void* d_out, int out_size, void* d_ws, size_t ws_size,
                              hipStream_t stream)
{
    const float* X  = (const float*)d_in[0];
    const float* Wq = (const float*)d_in[1];
    const float* Wk = (const float*)d_in[2];
    const float* Wv = (const float*)d_in[3];
    const float* Wo = (const float*)d_in[4];
    const int* tpos = (const int*)d_in[5];
    float* out = (float*)d_out;
    char* ws = (char*)d_ws;

    const size_t MB = (size_t)1 << 20;
    u16* Xb   = (u16*)(ws + 0);        // 8 MB; reused as Vt after proj GEMMs
    u16* WqB  = (u16*)(ws + 8 * MB);
    u16* WkB  = (u16*)(ws + 10 * MB);
    u16* WvB  = (u16*)(ws + 12 * MB);
    u16* WoB  = (u16*)(ws + 14 * MB);
    u16* Qraw = (u16*)(ws + 16 * MB);  // 8 MB; reused as AttnOut after rope
    u16* Kraw = (u16*)(ws + 24 * MB);
    u16* Vraw = (u16*)(ws + 32 * MB);
    u16* Qt   = (u16*)(ws + 40 * MB);
    u16* Kt   = (u16*)(ws + 48 * MB);
    u16* Vt   = Xb;
    u16* AOut = Qraw;

    cvt_kernel<<<4096, 256, 0, stream>>>(X, Xb, MROWS * D_MODEL / 4);
    cvt4_kernel<<<dim3(1024, 4), 256, 0, stream>>>(Wq, Wk, Wv, Wo,
                                                   WqB, WkB, WvB, WoB,
                                                   D_MODEL * D_MODEL / 4);

    gemm_bt<0><<<dim3(32, 8, 3), 256, 0, stream>>>(Xb, WqB, WkB, WvB,
                                                   Qraw, Kraw, Vraw,
                                                   MROWS, D_MODEL, D_MODEL);
    rope_qk<<<8192, 256, 0, stream>>>(Qraw, Kraw, tpos, Qt, Kt);
    vtrans<<<dim3(32, 16, 2), 256, 0, stream>>>(Vraw, Vt);
    attn_kernel<<<dim3(32, 16, 2), 256, 0, stream>>>(Qt, Kt, Vt, AOut);
    gemm_bt<1><<<dim3(32, 8, 1), 256, 0, stream>>>(AOut, WoB, WoB, WoB,
                                                   out, out, out,
                                                   MROWS, D_MODEL, D_MODEL);
}